// Round 3
// baseline (579.544 us; speedup 1.0000x reference)
//
#include <hip/hip_runtime.h>

#define MM 1024
#define NN 4096
#define DD 128
#define HH 32
#define LL 4096
#define PP 2048

typedef __attribute__((ext_vector_type(8))) short short8;
typedef __attribute__((ext_vector_type(4))) float f32x4;

__device__ __forceinline__ ushort f2bf(float f) {
  unsigned u = __builtin_bit_cast(unsigned, f);
  u += 0x7fffu + ((u >> 16) & 1u);
  return (ushort)(u >> 16);
}

__device__ __forceinline__ void gl_lds16(const void* g, void* l) {
  __builtin_amdgcn_global_load_lds(
      (const __attribute__((address_space(1))) void*)g,
      (__attribute__((address_space(3))) void*)l, 16, 0, 0);
}

// ---------------- fp32 -> bf16 convert (8 elts/thread) ----------------
__global__ __launch_bounds__(256) void convert_kernel(
    const float* __restrict__ src, ushort* __restrict__ dst, int n8) {
  int i = blockIdx.x * 256 + threadIdx.x;
  if (i >= n8) return;
  const float4* s = (const float4*)src + (size_t)i * 2;
  float4 a = s[0], b = s[1];
  union { ushort s[8]; uint4 v; } pk;
  pk.s[0] = f2bf(a.x); pk.s[1] = f2bf(a.y);
  pk.s[2] = f2bf(a.z); pk.s[3] = f2bf(a.w);
  pk.s[4] = f2bf(b.x); pk.s[5] = f2bf(b.y);
  pk.s[6] = f2bf(b.z); pk.s[7] = f2bf(b.w);
  ((uint4*)dst)[i] = pk.v;
}

// ------- transpose+convert W (3x fp32 [N,N] -> bf16 Wt[j][k] = W[k][j]) -------
__global__ __launch_bounds__(256) void transpose_w_kernel(
    const float* __restrict__ W0, const float* __restrict__ W1,
    const float* __restrict__ W2, ushort* __restrict__ Wt) {
  __shared__ __align__(16) ushort tile[64][72];  // 144B pitch (16B-aligned)
  int z = blockIdx.z;
  const float* W = (z == 0) ? W0 : ((z == 1) ? W1 : W2);
  ushort* out = Wt + (size_t)z * NN * NN;
  int r0 = blockIdx.x * 64, c0 = blockIdx.y * 64;
  int t = threadIdx.x;
#pragma unroll
  for (int i = 0; i < 4; ++i) {
    int c = i * 256 + t;
    int r = c >> 4, cc = (c & 15) * 4;
    float4 v = *(const float4*)(W + (size_t)(r0 + r) * NN + c0 + cc);
    tile[r][cc + 0] = f2bf(v.x);
    tile[r][cc + 1] = f2bf(v.y);
    tile[r][cc + 2] = f2bf(v.z);
    tile[r][cc + 3] = f2bf(v.w);
  }
  __syncthreads();
#pragma unroll
  for (int i = 0; i < 2; ++i) {
    int c = i * 256 + t;
    int j = c >> 3, kk = (c & 7) * 8;
    union { ushort s[8]; uint4 v; } pk;
#pragma unroll
    for (int u = 0; u < 8; ++u) pk.s[u] = tile[kk + u][j];
    *(uint4*)(out + (size_t)(c0 + j) * NN + r0 + kk) = pk.v;
  }
}

// --- build bf16 Vt[h][d][l] from fp32 cache_V (+ bf16 new v rows at P..P+M) ---
__global__ __launch_bounds__(256) void transpose_v_kernel(
    const float* __restrict__ cacheV, const ushort* __restrict__ v_new,
    ushort* __restrict__ Vt) {
  __shared__ __align__(16) ushort tile[64][72];
  int l0 = blockIdx.x * 64, d0 = blockIdx.y * 64, h = blockIdx.z;
  int t = threadIdx.x;
  bool isnew = (l0 >= PP && l0 < PP + MM);
  if (isnew) {
    const ushort* src = v_new + (size_t)(l0 - PP) * NN + h * DD + d0;
#pragma unroll
    for (int i = 0; i < 2; ++i) {
      int c = i * 256 + t;
      int r = c >> 3, cc = (c & 7) * 8;
      *(uint4*)&tile[r][cc] = *(const uint4*)(src + (size_t)r * NN + cc);
    }
  } else {
    const float* src = cacheV + ((size_t)h * LL + l0) * DD + d0;
#pragma unroll
    for (int i = 0; i < 4; ++i) {
      int c = i * 256 + t;
      int r = c >> 4, cc = (c & 15) * 4;
      float4 v = *(const float4*)(src + (size_t)r * DD + cc);
      tile[r][cc + 0] = f2bf(v.x);
      tile[r][cc + 1] = f2bf(v.y);
      tile[r][cc + 2] = f2bf(v.z);
      tile[r][cc + 3] = f2bf(v.w);
    }
  }
  __syncthreads();
#pragma unroll
  for (int i = 0; i < 2; ++i) {
    int c = i * 256 + t;
    int j = c >> 3, kk = (c & 7) * 8;
    union { ushort s[8]; uint4 v; } pk;
#pragma unroll
    for (int u = 0; u < 8; ++u) pk.s[u] = tile[kk + u][j];
    *(uint4*)(Vt + ((size_t)(h * DD + d0 + j)) * LL + l0 + kk) = pk.v;
  }
}

// ---------------- QKV GEMM: C[m][col] = sum_k Xb[m][k] * Wt[col][k] ----------------
// 128x128 tile, BK=64, global_load_lds(16B), XOR-swizzled LDS chunks.
__global__ __launch_bounds__(256) void qkv_gemm_kernel(
    const ushort* __restrict__ X, const ushort* __restrict__ Wt,
    ushort* __restrict__ q_ws, ushort* __restrict__ k_ws,
    ushort* __restrict__ v_ws) {
  __shared__ __align__(16) ushort Alds[128 * 64];
  __shared__ __align__(16) ushort Blds[128 * 64];
  int t = threadIdx.x;
  int lane = t & 63, quad = lane >> 4, l15 = lane & 15;
  int wv = t >> 6, wm = wv >> 1, wn = wv & 1;
  int m0 = blockIdx.x * 128;
  int wsel = blockIdx.y >> 5;
  int col0 = (blockIdx.y & 31) * 128;
  const ushort* Wsrc = Wt + (size_t)wsel * NN * NN + (size_t)col0 * NN;
  ushort* dst = (wsel == 0) ? q_ws : ((wsel == 1) ? k_ws : v_ws);

  int wuni = __builtin_amdgcn_readfirstlane(t & 192);  // wave base thread

  const ushort* aG[4];
  const ushort* bG[4];
  unsigned ldsb[4];
#pragma unroll
  for (int i = 0; i < 4; ++i) {
    int c = i * 256 + t;
    int row = c >> 3, g = (c & 7) ^ (row & 7);
    aG[i] = X + (size_t)(m0 + row) * NN + g * 8;
    bG[i] = Wsrc + (size_t)row * NN + g * 8;
    ldsb[i] = (unsigned)(i * 256 + wuni) * 16u;
  }
  unsigned aAddr[4][2], bAddr[4][2];
#pragma unroll
  for (int mb = 0; mb < 4; ++mb)
#pragma unroll
    for (int s = 0; s < 2; ++s) {
      int row = wm * 64 + mb * 16 + l15;
      int g = s * 4 + quad;
      aAddr[mb][s] = (unsigned)(row * 128 + ((g ^ (row & 7)) * 16));
    }
#pragma unroll
  for (int nb = 0; nb < 4; ++nb)
#pragma unroll
    for (int s = 0; s < 2; ++s) {
      int row = wn * 64 + nb * 16 + l15;
      int g = s * 4 + quad;
      bAddr[nb][s] = (unsigned)(row * 128 + ((g ^ (row & 7)) * 16));
    }

  f32x4 acc[4][4];
#pragma unroll
  for (int mb = 0; mb < 4; ++mb)
#pragma unroll
    for (int nb = 0; nb < 4; ++nb) acc[mb][nb] = (f32x4){0.f, 0.f, 0.f, 0.f};

  for (int kt = 0; kt < 64; ++kt) {
#pragma unroll
    for (int i = 0; i < 4; ++i) gl_lds16(aG[i], (char*)Alds + ldsb[i]);
#pragma unroll
    for (int i = 0; i < 4; ++i) gl_lds16(bG[i], (char*)Blds + ldsb[i]);
#pragma unroll
    for (int i = 0; i < 4; ++i) { aG[i] += 64; bG[i] += 64; }
    __syncthreads();  // drains vmcnt -> tiles visible
#pragma unroll
    for (int s = 0; s < 2; ++s) {
      short8 af[4], bf[4];
#pragma unroll
      for (int mb = 0; mb < 4; ++mb)
        af[mb] = *(const short8*)((const char*)Alds + aAddr[mb][s]);
#pragma unroll
      for (int nb = 0; nb < 4; ++nb)
        bf[nb] = *(const short8*)((const char*)Blds + bAddr[nb][s]);
#pragma unroll
      for (int mb = 0; mb < 4; ++mb)
#pragma unroll
        for (int nb = 0; nb < 4; ++nb)
          acc[mb][nb] = __builtin_amdgcn_mfma_f32_16x16x32_bf16(
              af[mb], bf[nb], acc[mb][nb], 0, 0, 0);
    }
    __syncthreads();  // done reading before next stage overwrites
  }

#pragma unroll
  for (int mb = 0; mb < 4; ++mb)
#pragma unroll
    for (int nb = 0; nb < 4; ++nb)
#pragma unroll
      for (int r = 0; r < 4; ++r) {
        int row = m0 + wm * 64 + mb * 16 + quad * 4 + r;
        int col = col0 + wn * 64 + nb * 16 + l15;
        dst[(size_t)row * NN + col] = f2bf(acc[mb][nb][r]);
      }
}

// ---------------- fused attention: one head x 64 queries per block ----------------
// LDS-traffic-minimized design: only P goes through LDS.
//   - QK^T l-split: wave wv owns l-cols [wv*16, wv*16+16) of each 64-l tile;
//     holds FULL 64x128 Q tile as A-frags in regs (64 VGPR); K slice loaded
//     direct global->reg as B-frags (4 short8), double-buffered.
//   - PV d-split (as before): wave owns d-rows [wv*32, +32); V^T slice loaded
//     direct global->reg as A-frags (4 short8), double-buffered.
//   - P (64x64 bf16) through LDS, pitch 144B (bank-balanced read/write).
//   - 2 raw s_barriers/iter with lgkmcnt-only waits; K/V prefetch one full
//     tile ahead stays in flight across barriers (counted vmcnt by compiler).
//   - denominator: per-wave partials in regs, reduced once in epilogue.
__global__ __launch_bounds__(256, 2) void attn_kernel(
    const ushort* __restrict__ q_ws, const ushort* __restrict__ k_ws,
    const ushort* __restrict__ Kb, const ushort* __restrict__ Vt,
    float* __restrict__ out) {
  // LDS: Plds [64m][72 ushorts] @0 (9216B); den float[4][64] @34816 (1024B);
  //      Olds float[64][136] @0 (34816B, epilogue reuse). Total 35840B.
  __shared__ __align__(16) char smem[35840];
  ushort* Plds = (ushort*)smem;
  float* denlds = (float*)(smem + 34816);
  float* Olds = (float*)smem;

  int t = threadIdx.x;
  int lane = t & 63, quad = lane >> 4, l15 = lane & 15;
  int wv = t >> 6;
  int quad8 = quad * 8, quad4 = quad * 4, wv16 = wv * 16;
  int wv16l15 = wv16 + l15;
  // XCD-aware bijective swizzle (512 % 8 == 0): 4 heads per XCD -> K/V L2-hot.
  int flat = (int)(blockIdx.y * 16 + blockIdx.x);
  int swz = ((flat & 7) << 6) | (flat >> 3);
  int m0 = (swz & 15) * 64;
  int h = swz >> 4;

  // Q: full 64-row tile as A-frags [mb][ds]: row m0+mb*16+l15, d = ds*32+quad*8
  short8 qf[4][4];
#pragma unroll
  for (int mb = 0; mb < 4; ++mb) {
    const ushort* qr =
        q_ws + (size_t)(m0 + mb * 16 + l15) * NN + h * DD + quad8;
#pragma unroll
    for (int ds = 0; ds < 4; ++ds) qf[mb][ds] = *(const short8*)(qr + ds * 32);
  }

  // V row base for this wave: d = wv*32 + l15 (db=0) and +16 (db=1)
  const ushort* vrow = Vt + ((size_t)(h * DD + wv * 32 + l15)) * LL;
  const ushort* vrow16 = vrow + (size_t)16 * LL;

  f32x4 Oacc[2][4];
#pragma unroll
  for (int db = 0; db < 2; ++db)
#pragma unroll
    for (int mb = 0; mb < 4; ++mb) Oacc[db][mb] = (f32x4){0.f, 0.f, 0.f, 0.f};
  float denp[4][4];
#pragma unroll
  for (int mb = 0; mb < 4; ++mb)
#pragma unroll
    for (int r = 0; r < 4; ++r) denp[mb][r] = 0.f;

  short8 kra[4], krb[4], vra[2][2], vrb[2][2];

  // prologue: tile 0 (l0=0 < PP -> Kb region)
  {
    const ushort* kp = Kb + ((size_t)h * LL + wv16l15) * DD;
    kra[0] = *(const short8*)(kp + quad8);
    kra[1] = *(const short8*)(kp + 32 + quad8);
    kra[2] = *(const short8*)(kp + 64 + quad8);
    kra[3] = *(const short8*)(kp + 96 + quad8);
    vra[0][0] = *(const short8*)(vrow + quad8);
    vra[0][1] = *(const short8*)(vrow + 32 + quad8);
    vra[1][0] = *(const short8*)(vrow16 + quad8);
    vra[1][1] = *(const short8*)(vrow16 + 32 + quad8);
  }

#define ATTN_STEP(LT, KC, VC, KN, VN, PF)                                      \
  do {                                                                         \
    if (PF) { /* prefetch tile LT+1 into KN/VN (consumed next step) */         \
      int l0n = ((LT) + 1) << 6;                                               \
      size_t krow = (size_t)l0n + (size_t)wv16l15;                             \
      const ushort* kp = (l0n >= PP && l0n < PP + MM)                          \
                             ? k_ws + (krow - PP) * NN + h * DD                \
                             : Kb + ((size_t)h * LL + krow) * DD;              \
      KN[0] = *(const short8*)(kp + quad8);                                    \
      KN[1] = *(const short8*)(kp + 32 + quad8);                               \
      KN[2] = *(const short8*)(kp + 64 + quad8);                               \
      KN[3] = *(const short8*)(kp + 96 + quad8);                               \
      const ushort* vp0 = vrow + l0n;                                          \
      const ushort* vp1 = vrow16 + l0n;                                        \
      VN[0][0] = *(const short8*)(vp0 + quad8);                                \
      VN[0][1] = *(const short8*)(vp0 + 32 + quad8);                           \
      VN[1][0] = *(const short8*)(vp1 + quad8);                                \
      VN[1][1] = *(const short8*)(vp1 + 32 + quad8);                           \
    }                                                                          \
    /* QK^T: S[64m][16l-slice]; C: col=l15 (l), row=quad*4+r (m within mb) */  \
    f32x4 sac[4];                                                              \
    __builtin_amdgcn_s_setprio(1);                                             \
    _Pragma("unroll") for (int mb = 0; mb < 4; ++mb) {                         \
      f32x4 s = (f32x4){0.f, 0.f, 0.f, 0.f};                                   \
      s = __builtin_amdgcn_mfma_f32_16x16x32_bf16(qf[mb][0], KC[0], s, 0, 0, 0);\
      s = __builtin_amdgcn_mfma_f32_16x16x32_bf16(qf[mb][1], KC[1], s, 0, 0, 0);\
      s = __builtin_amdgcn_mfma_f32_16x16x32_bf16(qf[mb][2], KC[2], s, 0, 0, 0);\
      s = __builtin_amdgcn_mfma_f32_16x16x32_bf16(qf[mb][3], KC[3], s, 0, 0, 0);\
      sac[mb] = s;                                                             \
    }                                                                          \
    __builtin_amdgcn_s_setprio(0);                                             \
    _Pragma("unroll") for (int mb = 0; mb < 4; ++mb) {                         \
      float e0 = __expf(sac[mb][0]), e1 = __expf(sac[mb][1]);                  \
      float e2 = __expf(sac[mb][2]), e3 = __expf(sac[mb][3]);                  \
      denp[mb][0] += e0; denp[mb][1] += e1;                                    \
      denp[mb][2] += e2; denp[mb][3] += e3;                                    \
      ushort* pw = Plds + (mb * 16 + quad4) * 72 + wv16l15;                    \
      pw[0] = f2bf(e0); pw[72] = f2bf(e1);                                     \
      pw[144] = f2bf(e2); pw[216] = f2bf(e3);                                  \
    }                                                                          \
    asm volatile("s_waitcnt lgkmcnt(0)" ::: "memory");                         \
    __builtin_amdgcn_s_barrier(); /* P ready (vmcnt prefetch stays live) */    \
    /* PV: O^T[32d][64m] per wave; A=V^T frags (regs), B=P frags (LDS) */      \
    __builtin_amdgcn_s_setprio(1);                                             \
    _Pragma("unroll") for (int mb = 0; mb < 4; ++mb) {                         \
      const ushort* pr = Plds + (mb * 16 + l15) * 72 + quad8;                  \
      short8 p0 = *(const short8*)pr;                                          \
      short8 p1 = *(const short8*)(pr + 32);                                   \
      Oacc[0][mb] = __builtin_amdgcn_mfma_f32_16x16x32_bf16(VC[0][0], p0,      \
                                                            Oacc[0][mb], 0, 0, 0);\
      Oacc[0][mb] = __builtin_amdgcn_mfma_f32_16x16x32_bf16(VC[0][1], p1,      \
                                                            Oacc[0][mb], 0, 0, 0);\
      Oacc[1][mb] = __builtin_amdgcn_mfma_f32_16x16x32_bf16(VC[1][0], p0,      \
                                                            Oacc[1][mb], 0, 0, 0);\
      Oacc[1][mb] = __builtin_amdgcn_mfma_f32_16x16x32_bf16(VC[1][1], p1,      \
                                                            Oacc[1][mb], 0, 0, 0);\
    }                                                                          \
    __builtin_amdgcn_s_setprio(0);                                             \
    asm volatile("s_waitcnt lgkmcnt(0)" ::: "memory");                         \
    __builtin_amdgcn_s_barrier(); /* P consumed -> next step may overwrite */  \
  } while (0)

  for (int i = 0; i < 31; ++i) {
    ATTN_STEP(2 * i, kra, vra, krb, vrb, 1);
    ATTN_STEP(2 * i + 1, krb, vrb, kra, vra, 1);
  }
  ATTN_STEP(62, kra, vra, krb, vrb, 1);
  ATTN_STEP(63, krb, vrb, kra, vra, 0);
#undef ATTN_STEP

  // ---- epilogue: denominator reduce (sum over l) ----
#pragma unroll
  for (int mb = 0; mb < 4; ++mb)
#pragma unroll
    for (int r = 0; r < 4; ++r) {
      float v = denp[mb][r];
      v += __shfl_xor(v, 1);
      v += __shfl_xor(v, 2);
      v += __shfl_xor(v, 4);
      v += __shfl_xor(v, 8);
      denp[mb][r] = v;
    }
  if (l15 == 0) {
#pragma unroll
    for (int mb = 0; mb < 4; ++mb)
#pragma unroll
      for (int r = 0; r < 4; ++r)
        denlds[wv * 64 + mb * 16 + quad4 + r] = denp[mb][r];
  }
  __syncthreads();

  // divide + transpose O^T -> O via LDS (fp32, pitch 136)
#pragma unroll
  for (int mb = 0; mb < 4; ++mb) {
    int m = mb * 16 + l15;
    float den =
        denlds[m] + denlds[64 + m] + denlds[128 + m] + denlds[192 + m];
    float inv = 1.0f / den;
#pragma unroll
    for (int db = 0; db < 2; ++db)
#pragma unroll
      for (int r = 0; r < 4; ++r) {
        int d = wv * 32 + db * 16 + quad4 + r;
        Olds[m * 136 + d] = Oacc[db][mb][r] * inv;
      }
  }
  __syncthreads();
  {
    int m = t >> 2, c0 = (t & 3) * 32;
    float* orow = out + (size_t)(m0 + m) * NN + h * DD + c0;
#pragma unroll
    for (int j = 0; j < 32; j += 4) {
      float4 v;
      v.x = Olds[m * 136 + c0 + j + 0];
      v.y = Olds[m * 136 + c0 + j + 1];
      v.z = Olds[m * 136 + c0 + j + 2];
      v.w = Olds[m * 136 + c0 + j + 3];
      *(float4*)(orow + j) = v;
    }
  }
}

extern "C" void kernel_launch(void* const* d_in, const int* in_sizes, int n_in,
                              void* d_out, int out_size, void* d_ws,
                              size_t ws_size, hipStream_t stream) {
  const float* X = (const float*)d_in[0];
  const float* Wq = (const float*)d_in[1];
  const float* Wk = (const float*)d_in[2];
  const float* Wv = (const float*)d_in[3];
  const float* cK = (const float*)d_in[4];
  const float* cV = (const float*)d_in[5];
  float* out = (float*)d_out;
  char* wsb = (char*)d_ws;

  // ws layout (bytes) — Kb/Vt alias Wt (dead after GEMM). Total 128 MiB.
  ushort* Wt = (ushort*)wsb;                         // 100,663,296
  ushort* Kb = (ushort*)wsb;                         // 33,554,432 (alias)
  ushort* Vt = (ushort*)(wsb + 33554432);            // 33,554,432 (alias)
  ushort* Xb = (ushort*)(wsb + 100663296);           // 8,388,608
  ushort* q_ws = (ushort*)(wsb + 109051904);         // 8,388,608
  ushort* k_ws = (ushort*)(wsb + 117440512);         // 8,388,608
  ushort* v_ws = (ushort*)(wsb + 125829120);         // 8,388,608

  convert_kernel<<<2048, 256, 0, stream>>>(X, Xb, MM * NN / 8);
  transpose_w_kernel<<<dim3(64, 64, 3), 256, 0, stream>>>(Wq, Wk, Wv, Wt);
  qkv_gemm_kernel<<<dim3(8, 96), 256, 0, stream>>>(Xb, Wt, q_ws, k_ws, v_ws);
  convert_kernel<<<8192, 256, 0, stream>>>(cK, Kb, HH * LL * DD / 8);
  transpose_v_kernel<<<dim3(64, 2, 32), 256, 0, stream>>>(cV, v_ws, Vt);
  attn_kernel<<<dim3(16, 32), 256, 0, stream>>>(q_ws, k_ws, Kb, Vt, out);
}